// Round 2
// baseline (677.636 us; speedup 1.0000x reference)
//
#include <hip/hip_runtime.h>

// out[b, r, c] = (c >= r) ? in[b, triu_index(r, c)] : 0
// triu_index(r, c) = row_base(r) + c, row_base = r*M - r*(r-1)/2 - r
//
// Layout: one wave (64 lanes) handles one output row (1024 cols).
// Column-block loop j=0..3: lanes cover cols 256j + 4*lane .. +3.
// Block classification (all-upper / all-zero / mixed) is wave-uniform.
// Reads: misalignment sh = row_base & 3 is wave-uniform; aligned dense
// dwordx4 lo/hi loads + uniform 4-way select replace 4 strided dword loads.

constexpr int M = 1024;
constexpr int BATCH = 128;
constexpr int TRIU_LEN = M * (M + 1) / 2;  // 524800 (divisible by 4)

__global__ __launch_bounds__(256) void triu_scatter_v2(
    const float* __restrict__ in, float* __restrict__ out) {
    int tid  = blockIdx.x * blockDim.x + threadIdx.x;  // 0 .. 128*1024*64-1
    int lane = tid & 63;                               // one wave = one row
    int r    = (tid >> 6) & (M - 1);
    int b    = tid >> 16;

    int row_base = r * M - (r * (r - 1)) / 2 - r;      // in-index of (r,c) = row_base + c
    const float* inb = in + (size_t)b * TRIU_LEN;
    float* outr = out + ((size_t)b * M + r) * M;       // output row pointer

    int sh = row_base & 3;                             // wave-uniform shift

    #pragma unroll
    for (int j = 0; j < 4; ++j) {
        int C = (j << 8) + (lane << 2);                // first col this lane handles in block j
        float4 v;
        if ((j << 8) >= r) {
            // whole 256-col block in upper triangle (wave-uniform branch)
            int idx0 = row_base + C;                   // idx0 - sh is 0 mod 4
            const float* base = inb + (idx0 - sh);
            float4 lo = *reinterpret_cast<const float4*>(base);
            if (sh == 0) {
                v = lo;
            } else {
                float4 hi = *reinterpret_cast<const float4*>(base + 4);  // <=3 floats overread, in-bounds
                if (sh == 1)      v = make_float4(lo.y, lo.z, lo.w, hi.x);
                else if (sh == 2) v = make_float4(lo.z, lo.w, hi.x, hi.y);
                else              v = make_float4(lo.w, hi.x, hi.y, hi.z);
            }
        } else if ((j << 8) + 255 < r) {
            // whole block strictly below diagonal
            v = make_float4(0.f, 0.f, 0.f, 0.f);
        } else {
            // boundary block (1 of 4 per row): per-element predication
            int idx0 = row_base + C;
            v.x = (C     >= r) ? inb[idx0]     : 0.f;
            v.y = (C + 1 >= r) ? inb[idx0 + 1] : 0.f;
            v.z = (C + 2 >= r) ? inb[idx0 + 2] : 0.f;
            v.w = (C + 3 >= r) ? inb[idx0 + 3] : 0.f;
        }
        *reinterpret_cast<float4*>(outr + C) = v;      // dense, 16B-aligned
    }
}

extern "C" void kernel_launch(void* const* d_in, const int* in_sizes, int n_in,
                              void* d_out, int out_size, void* d_ws, size_t ws_size,
                              hipStream_t stream) {
    const float* in = (const float*)d_in[0];
    float* out = (float*)d_out;

    const int total_threads = BATCH * M * 64;          // 8,388,608
    const int block = 256;
    const int grid = total_threads / block;            // 32768

    triu_scatter_v2<<<grid, block, 0, stream>>>(in, out);
}